// Round 13
// baseline (166.960 us; speedup 1.0000x reference)
//
#include <hip/hip_runtime.h>
#include <math.h>

#define NRAYS 8192
#define T 128
#define H 128
#define SHD 16

using short8 = __attribute__((ext_vector_type(8))) short;
using f32x4  = __attribute__((ext_vector_type(4))) float;
using f32x2  = __attribute__((ext_vector_type(2))) float;

__device__ __forceinline__ float fexp(float x) {
  return exp2f(x * 1.44269504088896341f);
}
__device__ __forceinline__ float softplus_f(float x) {
  return fmaxf(x, 0.f) + 0.693147180559945309f * log2f(1.f + fexp(-fabsf(x)));
}
__device__ __forceinline__ float sigmoid_f(float x) {
  return __builtin_amdgcn_rcpf(1.f + fexp(-x));
}

// RNE float->bf16 (preprocess only)
__device__ __forceinline__ unsigned f2bf(float f) {
  unsigned u = __float_as_uint(f);
  return (u + 0x7fffu + ((u >> 16) & 1u)) >> 16;
}

// RNE bf16 pack of a float pair: single VALU op (v_cvt_pk_bf16_f32, gfx950)
__device__ __forceinline__ unsigned pk2(f32x2 h) {
  unsigned r;
  asm("v_cvt_pk_bf16_f32 %0, %1, %2" : "=v"(r) : "v"(h[0]), "v"(h[1]));
  return r;
}

// DPP row_shr:N add-scan step on the VALU pipe (R10-proven)
template<int N>
__device__ __forceinline__ float dpp_shr0(float v) {
  return __builtin_bit_cast(float,
    __builtin_amdgcn_update_dpp(0, __builtin_bit_cast(int, v),
                                0x110 | N, 0xf, 0xf, false));
}
// 16-lane inclusive scan, pure VALU (valid within each 16-lane row)
__device__ __forceinline__ float scan16(float v) {
  v += dpp_shr0<1>(v);
  v += dpp_shr0<2>(v);
  v += dpp_shr0<4>(v);
  v += dpp_shr0<8>(v);
  return v;
}
__device__ __forceinline__ float readlane15f(float v) {
  return __builtin_bit_cast(float,
    __builtin_amdgcn_readlane(__builtin_bit_cast(int, v), 15));
}

// ---- preprocess (R1/R11 version — cheap) ----
// w2t: bf16 W2^T, XOR-swizzled: w2t[n*128 + p], octet o=(p>>3)^(n&7), k=o*8+(p&7)
// woutf[(kk*64+L)*8+j]: epilogue A-frag; rayp_all[r][8] = AABB + SH scalars.
__global__ void preprocess(const float* __restrict__ W2, const float* __restrict__ Wd,
                           const float* __restrict__ Wc, const float* __restrict__ bc,
                           const float* __restrict__ origins, const float* __restrict__ dirs,
                           unsigned short* __restrict__ w2t,
                           unsigned short* __restrict__ woutf,
                           float* __restrict__ rayp_all) {
  const int t = blockIdx.x * 256 + threadIdx.x;
  if (t < 16384) {
    const int n = t >> 7, p = t & 127;
    const int o = (p >> 3) ^ (n & 7);
    const int k = o * 8 + (p & 7);
    w2t[t] = (unsigned short)f2bf(W2[k * 128 + n]);
  }
  if (t < 2048) {
    const int kk = t >> 9, L = (t >> 3) & 63, j = t & 7;
    const int c = L & 15, g = L >> 4;
    const int k = kk * 32 + g * 8 + j;
    float v = 0.f;
    if (c == 0) v = Wd[k];
    else if (c < 4) v = Wc[k * 3 + (c - 1)];
    woutf[t] = (unsigned short)f2bf(v);
  }
  if (t < NRAYS) {
    const float ox = origins[t*3+0], oy = origins[t*3+1], oz = origins[t*3+2];
    const float dx = dirs[t*3+0],  dy = dirs[t*3+1],  dz = dirs[t*3+2];
    const float ix = 1.f/dx, iy = 1.f/dy, iz = 1.f/dz;
    const float t1x = (-1.f-ox)*ix, t2x = (1.f-ox)*ix;
    const float t1y = (-1.f-oy)*iy, t2y = (1.f-oy)*iy;
    const float t1z = (-1.f-oz)*iz, t2z = (1.f-oz)*iz;
    float tnear = fmaxf(fmaxf(fminf(t1x,t2x), fminf(t1y,t2y)), fminf(t1z,t2z));
    tnear = fmaxf(tnear, 0.f);
    const float tfar = fminf(fminf(fmaxf(t1x,t2x), fmaxf(t1y,t2y)), fmaxf(t1z,t2z));
    const bool  active = tfar > tnear;
    const float tfar_c = fmaxf(tfar, tnear + 1e-3f);
    const float dnorm = sqrtf(dx*dx + dy*dy + dz*dz);
    const float nx = dx/dnorm, ny = dy/dnorm, nz = dz/dnorm;
    const float x2 = nx*nx, y2 = ny*ny, z2 = nz*nz;
    const float xy = nx*ny, yz = ny*nz, xz = nx*nz;
    float ynm[16];
    ynm[0]  = 0.282094791773878f;
    ynm[1]  = -0.48860251190292f*ny;
    ynm[2]  = 0.48860251190292f*nz;
    ynm[3]  = -0.48860251190292f*nx;
    ynm[4]  = 1.0925484305920792f*xy;
    ynm[5]  = -1.0925484305920792f*yz;
    ynm[6]  = 0.94617469575756f*z2 - 0.31539156525252f;
    ynm[7]  = -1.0925484305920792f*xz;
    ynm[8]  = 0.5462742152960396f*(x2-y2);
    ynm[9]  = 0.5900435899266435f*ny*(-3.f*x2+y2);
    ynm[10] = 2.8906114426405538f*xy*nz;
    ynm[11] = 0.4570457994644658f*ny*(1.f-5.f*z2);
    ynm[12] = 0.3731763325901154f*nz*(5.f*z2-3.f);
    ynm[13] = 0.4570457994644658f*nx*(1.f-5.f*z2);
    ynm[14] = 1.445305721320277f*nz*(x2-y2);
    ynm[15] = 0.5900435899266435f*nx*(-x2+3.f*y2);
    float cp0 = bc[0], cp1 = bc[1], cp2 = bc[2];
    #pragma unroll
    for (int s = 0; s < SHD; ++s) {
      cp0 = fmaf(ynm[s], Wc[(H+s)*3+0], cp0);
      cp1 = fmaf(ynm[s], Wc[(H+s)*3+1], cp1);
      cp2 = fmaf(ynm[s], Wc[(H+s)*3+2], cp2);
    }
    rayp_all[t*8+0] = tfar_c;
    rayp_all[t*8+1] = dnorm;
    rayp_all[t*8+2] = active ? 1.f : 0.f;
    rayp_all[t*8+3] = cp0;
    rayp_all[t*8+4] = cp1;
    rayp_all[t*8+5] = cp2;
    rayp_all[t*8+6] = tnear;
    rayp_all[t*8+7] = 0.f;
  }
}

// PERSISTENT BLOCKS: grid = 1024 = 4 blocks/CU x 256 CU exactly; each block
// stages W2 ONCE then loops over 8 rays. R12 post-mortem: staging TRAFFIC is
// not the bottleneck, per-ray fixed latency (stage + barriers + drain) is —
// persistence removes the stage phase from 7/8 rays and the block-drain tail.
// Per ray: setup -> B1 -> main loop (R11) -> epilogue (single slab, private,
// no barrier needed) -> per-wave tail (R2-style, DPP scan16) -> B2 (wtot
// stitch) -> B3 (wred) -> out. 3 barriers/ray vs 4, no stage/ray.
// LDS: Bs 32768 + As2 5120 + base/slope/ts/mask 2048 + wtot 16 + wred 64
//    = 40016 <= 40960 -> 4 blocks/CU at ~120 regs (56 VGPR + 64 AGPR).
__global__ __launch_bounds__(256, 4) void nerf_render(
    const float* __restrict__ origins, const float* __restrict__ dirs,
    const float* __restrict__ u, const float* __restrict__ W1,
    const float* __restrict__ b1, const float* __restrict__ b2,
    const float* __restrict__ bd, const unsigned short* __restrict__ w2t,
    const unsigned short* __restrict__ woutf, const float* __restrict__ rayp_all,
    float* __restrict__ out)
{
  const int tid = threadIdx.x;
  const int L = tid & 63;
  const int w = tid >> 6;
  const int g = L >> 4;
  const int c = L & 15;

  __shared__ __align__(16) short Bs[16384];     // swizzled W2^T (persistent)
  __shared__ __align__(16) short As2[4 * 640];  // per-wave epilogue slab
  __shared__ __align__(16) float baseA[H];
  __shared__ __align__(16) float slopeA[H];
  __shared__ __align__(16) float ts_s[T];
  __shared__ __align__(16) float mask_s[T];
  __shared__ float wtot[4];
  __shared__ float wred[4][4];

  // ---- stage W2 ONCE (covered by first B1) ----
  {
    const float4* src = (const float4*)w2t;
    float4* dst = (float4*)Bs;
    #pragma unroll
    for (int i = 0; i < 8; ++i) dst[tid + i * 256] = src[tid + i * 256];
  }

  // persistent epilogue A-frags (global, L2-hot)
  short8 wa[4];
  #pragma unroll
  for (int kk = 0; kk < 4; ++kk)
    wa[kk] = *(const short8*)&woutf[(kk*64 + L)*8];

  short* As2w = As2 + w * 640;
  const f32x2 zero2 = {0.f, 0.f};
  const float bd0 = bd[0];

  #pragma unroll 1
  for (int r = 0; r < 8; ++r) {
    const int ray = blockIdx.x * 8 + r;
    // per-ray scalars (uniform -> s_loads)
    const float tfar_c = rayp_all[ray*8+0];
    const float dnorm  = rayp_all[ray*8+1];
    const float actf   = rayp_all[ray*8+2];
    const float cpo0   = rayp_all[ray*8+3];
    const float cpo1   = rayp_all[ray*8+4];
    const float cpo2   = rayp_all[ray*8+5];
    const float tnear  = rayp_all[ray*8+6];

    // ---- per-sample setup (tid<128) ----
    if (tid < T) {
      const int tl = tid;
      const float ox = origins[ray*3+0], oy = origins[ray*3+1], oz = origins[ray*3+2];
      const float dx = dirs[ray*3+0],  dy = dirs[ray*3+1],  dz = dirs[ray*3+2];
      const bool active = actf != 0.f;
      const float ut = u[ray*T + tl];
      const float frac = ((float)tl + ut) * (1.f/(float)T);
      const float tt = tnear + (tfar_c - tnear) * frac;
      const float px = fmaf(dx, tt, ox);
      const float py = fmaf(dy, tt, oy);
      const float pz = fmaf(dz, tt, oz);
      ts_s[tl] = tt;
      const bool m = (fabsf(px) <= 1.f) && (fabsf(py) <= 1.f) && (fabsf(pz) <= 1.f) && active;
      mask_s[tl] = m ? 1.f : 0.f;
      const float w0v = W1[tl], w1v = W1[H + tl], w2v = W1[2*H + tl];
      baseA[tl]  = fmaf(ox, w0v, fmaf(oy, w1v, fmaf(oz, w2v, b1[tl])));
      slopeA[tl] = fmaf(dx, w0v, fmaf(dy, w1v, dz * w2v));
    }

    // ---- acc init = b2 (uniform global reads, L1/L2-hot) ----
    f32x4 acc[2][8];
    #pragma unroll
    for (int mt = 0; mt < 8; ++mt) {
      const float4 bv = *(const float4*)&b2[mt*16 + g*4];
      #pragma unroll
      for (int tm = 0; tm < 2; ++tm) {
        acc[tm][mt][0] = bv.x; acc[tm][mt][1] = bv.y;
        acc[tm][mt][2] = bv.z; acc[tm][mt][3] = bv.w;
      }
    }
    __syncthreads();   // B1: setup (and on r==0, stage) visible to all waves

    // ---- fused affine-layer1 + layer2 MFMA (R11-proven) ----
    const float t0 = ts_s[32*w + c];
    const float t1 = ts_s[32*w + 16 + c];
    const f32x2 tz0 = {t0, t0}, tz1 = {t1, t1};

    #pragma unroll
    for (int ks = 0; ks < 4; ++ks) {
      const int kb = ks*32 + g*8;
      const f32x4 bq0 = *(const f32x4*)&baseA[kb];
      const f32x4 bq1 = *(const f32x4*)&baseA[kb+4];
      const f32x4 sq0 = *(const f32x4*)&slopeA[kb];
      const f32x4 sq1 = *(const f32x4*)&slopeA[kb+4];
      const f32x2 b01 = {bq0[0], bq0[1]}, b23 = {bq0[2], bq0[3]};
      const f32x2 b45 = {bq1[0], bq1[1]}, b67 = {bq1[2], bq1[3]};
      const f32x2 s01 = {sq0[0], sq0[1]}, s23 = {sq0[2], sq0[3]};
      const f32x2 s45 = {sq1[0], sq1[1]}, s67 = {sq1[2], sq1[3]};
      const f32x2 a01 = __builtin_elementwise_max(__builtin_elementwise_fma(tz0, s01, b01), zero2);
      const f32x2 a23 = __builtin_elementwise_max(__builtin_elementwise_fma(tz0, s23, b23), zero2);
      const f32x2 a45 = __builtin_elementwise_max(__builtin_elementwise_fma(tz0, s45, b45), zero2);
      const f32x2 a67 = __builtin_elementwise_max(__builtin_elementwise_fma(tz0, s67, b67), zero2);
      const f32x2 e01 = __builtin_elementwise_max(__builtin_elementwise_fma(tz1, s01, b01), zero2);
      const f32x2 e23 = __builtin_elementwise_max(__builtin_elementwise_fma(tz1, s23, b23), zero2);
      const f32x2 e45 = __builtin_elementwise_max(__builtin_elementwise_fma(tz1, s45, b45), zero2);
      const f32x2 e67 = __builtin_elementwise_max(__builtin_elementwise_fma(tz1, s67, b67), zero2);
      union U { uint4 u; short8 s; } A0, A1;
      A0.u = make_uint4(pk2(a01), pk2(a23), pk2(a45), pk2(a67));
      A1.u = make_uint4(pk2(e01), pk2(e23), pk2(e45), pk2(e67));
      const int swb = ((ks*4 + g) ^ (c & 7)) * 8;   // swizzled octet (conflict-free)
      #pragma unroll
      for (int mt = 0; mt < 8; ++mt) {
        const short8 wf = *(const short8*)&Bs[(mt*16 + c)*128 + swb];
        acc[0][mt] = __builtin_amdgcn_mfma_f32_16x16x32_bf16(wf, A0.s, acc[0][mt], 0, 0, 0);
        acc[1][mt] = __builtin_amdgcn_mfma_f32_16x16x32_bf16(wf, A1.s, acc[1][mt], 0, 0, 0);
      }
    }

    // ---- epilogue: relu -> bf16 slab (per-wave private, no barrier) ----
    f32x4 osig[2];
    #pragma unroll
    for (int tm = 0; tm < 2; ++tm) {
      f32x4 oacc;
      oacc[0] = 0.f; oacc[1] = 0.f; oacc[2] = 0.f; oacc[3] = 0.f;
      #pragma unroll
      for (int kk = 0; kk < 4; ++kk) {
        #pragma unroll
        for (int i = 0; i < 2; ++i) {
          const f32x4 a = acc[tm][kk*2 + i];
          const f32x2 h01 = __builtin_elementwise_max((f32x2){a[0], a[1]}, zero2);
          const f32x2 h23 = __builtin_elementwise_max((f32x2){a[2], a[3]}, zero2);
          *(uint2*)&As2w[c*40 + i*16 + g*4] = make_uint2(pk2(h01), pk2(h23));
        }
        const short8 hbf = *(const short8*)&As2w[c*40 + g*8];
        oacc = __builtin_amdgcn_mfma_f32_16x16x32_bf16(wa[kk], hbf, oacc, 0, 0, 0);
      }
      osig[tm] = oacc;   // lanes g==0 hold {sigma_pre, c0, c1, c2}
    }

    // ---- per-wave online transmittance (valid in lanes 0..15, R2-proven) ----
    const int s0 = 32*w + c, s1 = s0 + 16;
    const float ts0 = ts_s[s0], tn0 = ts_s[s0 + 1];
    const float ts1 = ts_s[s1];
    const float tn1 = (s1 < T-1) ? ts_s[s1 + 1] : tfar_c * 10.f;
    const float d0 = mask_s[s0] * (tn0 - ts0) * dnorm;
    const float d1 = mask_s[s1] * (tn1 - ts1) * dnorm;
    const float sd0 = softplus_f(osig[0][0] + bd0) * d0;
    const float sd1 = softplus_f(osig[1][0] + bd0) * d1;
    float p0 = scan16(sd0);
    const float tot0 = readlane15f(p0);
    float p1 = scan16(sd1);
    const float tot1 = readlane15f(p1);
    if (L == 0) wtot[w] = tot0 + tot1;
    __syncthreads();   // B2: wtot ready
    float pre = 0.f;
    if (w > 0) pre += wtot[0];
    if (w > 1) pre += wtot[1];
    if (w > 2) pre += wtot[2];
    const float cs0 = pre + p0;
    const float cs1 = pre + tot0 + p1;
    const float w0 = fexp(sd0 - cs0) - fexp(-cs0);   // == 0 exactly when sd == 0
    const float w1 = fexp(sd1 - cs1) - fexp(-cs1);
    float pw  = w0 + w1;
    float pxc = w0 * sigmoid_f(osig[0][1] + cpo0) + w1 * sigmoid_f(osig[1][1] + cpo0);
    float pyc = w0 * sigmoid_f(osig[0][2] + cpo1) + w1 * sigmoid_f(osig[1][2] + cpo1);
    float pzc = w0 * sigmoid_f(osig[0][3] + cpo2) + w1 * sigmoid_f(osig[1][3] + cpo2);
    #pragma unroll
    for (int off = 1; off < 16; off <<= 1) {
      pw  += __shfl_xor(pw, off);
      pxc += __shfl_xor(pxc, off);
      pyc += __shfl_xor(pyc, off);
      pzc += __shfl_xor(pzc, off);
    }
    if (L == 0) {
      wred[w][0] = pw; wred[w][1] = pxc; wred[w][2] = pyc; wred[w][3] = pzc;
    }
    __syncthreads();   // B3: wred ready; also fences ts_s before next setup
    if (tid == 0) {
      const float aw = wred[0][0] + wred[1][0] + wred[2][0] + wred[3][0];
      const float o0 = wred[0][1] + wred[1][1] + wred[2][1] + wred[3][1];
      const float o1 = wred[0][2] + wred[1][2] + wred[2][2] + wred[3][2];
      const float o2 = wred[0][3] + wred[1][3] + wred[2][3] + wred[3][3];
      const bool act = actf != 0.f;
      float4 o;
      o.x = act ? o0 : 0.f;
      o.y = act ? o1 : 0.f;
      o.z = act ? o2 : 0.f;
      o.w = act ? aw : 0.f;
      *(float4*)&out[ray*4] = o;
    }
  }
}

extern "C" void kernel_launch(void* const* d_in, const int* in_sizes, int n_in,
                              void* d_out, int out_size, void* d_ws, size_t ws_size,
                              hipStream_t stream) {
  const float* origins = (const float*)d_in[0];
  const float* dirs    = (const float*)d_in[1];
  const float* u       = (const float*)d_in[2];
  const float* W1      = (const float*)d_in[3];
  const float* b1      = (const float*)d_in[4];
  const float* W2      = (const float*)d_in[5];
  const float* b2      = (const float*)d_in[6];
  const float* Wd      = (const float*)d_in[7];
  const float* bd      = (const float*)d_in[8];
  const float* Wc      = (const float*)d_in[9];
  const float* bc      = (const float*)d_in[10];

  unsigned short* w2t      = (unsigned short*)d_ws;
  unsigned short* woutf    = (unsigned short*)((char*)d_ws + 32768);
  float*          rayp_all = (float*)((char*)d_ws + 36864);

  preprocess<<<64, 256, 0, stream>>>(W2, Wd, Wc, bc, origins, dirs,
                                     w2t, woutf, rayp_all);
  nerf_render<<<NRAYS/8, 256, 0, stream>>>(origins, dirs, u, W1, b1, b2, bd,
                                           w2t, woutf, rayp_all, (float*)d_out);
}

// Round 14
// 159.119 us; speedup vs baseline: 1.0493x; 1.0493x over previous
//
#include <hip/hip_runtime.h>
#include <math.h>

#define NRAYS 8192
#define T 128
#define H 128
#define SHD 16

using short8 = __attribute__((ext_vector_type(8))) short;
using f32x4  = __attribute__((ext_vector_type(4))) float;
using f32x2  = __attribute__((ext_vector_type(2))) float;

__device__ __forceinline__ float fexp(float x) {
  return exp2f(x * 1.44269504088896341f);
}
__device__ __forceinline__ float softplus_f(float x) {
  return fmaxf(x, 0.f) + 0.693147180559945309f * log2f(1.f + fexp(-fabsf(x)));
}
__device__ __forceinline__ float sigmoid_f(float x) {
  return __builtin_amdgcn_rcpf(1.f + fexp(-x));
}

// RNE float->bf16 (preprocess only)
__device__ __forceinline__ unsigned f2bf(float f) {
  unsigned u = __float_as_uint(f);
  return (u + 0x7fffu + ((u >> 16) & 1u)) >> 16;
}

// RNE bf16 pack of a float pair: single VALU op (v_cvt_pk_bf16_f32, gfx950)
__device__ __forceinline__ unsigned pk2(f32x2 h) {
  unsigned r;
  asm("v_cvt_pk_bf16_f32 %0, %1, %2" : "=v"(r) : "v"(h[0]), "v"(h[1]));
  return r;
}

// DPP row_shr:N add-scan step on the VALU pipe (R10-proven)
template<int N>
__device__ __forceinline__ float dpp_shr0(float v) {
  return __builtin_bit_cast(float,
    __builtin_amdgcn_update_dpp(0, __builtin_bit_cast(int, v),
                                0x110 | N, 0xf, 0xf, false));
}
// 16-lane inclusive scan, pure VALU (valid within each 16-lane row)
__device__ __forceinline__ float scan16(float v) {
  v += dpp_shr0<1>(v);
  v += dpp_shr0<2>(v);
  v += dpp_shr0<4>(v);
  v += dpp_shr0<8>(v);
  return v;
}
__device__ __forceinline__ float readlane15f(float v) {
  return __builtin_bit_cast(float,
    __builtin_amdgcn_readlane(__builtin_bit_cast(int, v), 15));
}

// ---- preprocess (R1/R11 version — cheap) ----
// w2t: bf16 W2^T, XOR-swizzled: w2t[n*128 + p], octet o=(p>>3)^(n&7), k=o*8+(p&7)
// woutf[(kk*64+L)*8+j]: epilogue A-frag; rayp_all[r][8] = AABB + SH scalars.
__global__ void preprocess(const float* __restrict__ W2, const float* __restrict__ Wd,
                           const float* __restrict__ Wc, const float* __restrict__ bc,
                           const float* __restrict__ origins, const float* __restrict__ dirs,
                           unsigned short* __restrict__ w2t,
                           unsigned short* __restrict__ woutf,
                           float* __restrict__ rayp_all) {
  const int t = blockIdx.x * 256 + threadIdx.x;
  if (t < 16384) {
    const int n = t >> 7, p = t & 127;
    const int o = (p >> 3) ^ (n & 7);
    const int k = o * 8 + (p & 7);
    w2t[t] = (unsigned short)f2bf(W2[k * 128 + n]);
  }
  if (t < 2048) {
    const int kk = t >> 9, L = (t >> 3) & 63, j = t & 7;
    const int c = L & 15, g = L >> 4;
    const int k = kk * 32 + g * 8 + j;
    float v = 0.f;
    if (c == 0) v = Wd[k];
    else if (c < 4) v = Wc[k * 3 + (c - 1)];
    woutf[t] = (unsigned short)f2bf(v);
  }
  if (t < NRAYS) {
    const float ox = origins[t*3+0], oy = origins[t*3+1], oz = origins[t*3+2];
    const float dx = dirs[t*3+0],  dy = dirs[t*3+1],  dz = dirs[t*3+2];
    const float ix = 1.f/dx, iy = 1.f/dy, iz = 1.f/dz;
    const float t1x = (-1.f-ox)*ix, t2x = (1.f-ox)*ix;
    const float t1y = (-1.f-oy)*iy, t2y = (1.f-oy)*iy;
    const float t1z = (-1.f-oz)*iz, t2z = (1.f-oz)*iz;
    float tnear = fmaxf(fmaxf(fminf(t1x,t2x), fminf(t1y,t2y)), fminf(t1z,t2z));
    tnear = fmaxf(tnear, 0.f);
    const float tfar = fminf(fminf(fmaxf(t1x,t2x), fmaxf(t1y,t2y)), fmaxf(t1z,t2z));
    const bool  active = tfar > tnear;
    const float tfar_c = fmaxf(tfar, tnear + 1e-3f);
    const float dnorm = sqrtf(dx*dx + dy*dy + dz*dz);
    const float nx = dx/dnorm, ny = dy/dnorm, nz = dz/dnorm;
    const float x2 = nx*nx, y2 = ny*ny, z2 = nz*nz;
    const float xy = nx*ny, yz = ny*nz, xz = nx*nz;
    float ynm[16];
    ynm[0]  = 0.282094791773878f;
    ynm[1]  = -0.48860251190292f*ny;
    ynm[2]  = 0.48860251190292f*nz;
    ynm[3]  = -0.48860251190292f*nx;
    ynm[4]  = 1.0925484305920792f*xy;
    ynm[5]  = -1.0925484305920792f*yz;
    ynm[6]  = 0.94617469575756f*z2 - 0.31539156525252f;
    ynm[7]  = -1.0925484305920792f*xz;
    ynm[8]  = 0.5462742152960396f*(x2-y2);
    ynm[9]  = 0.5900435899266435f*ny*(-3.f*x2+y2);
    ynm[10] = 2.8906114426405538f*xy*nz;
    ynm[11] = 0.4570457994644658f*ny*(1.f-5.f*z2);
    ynm[12] = 0.3731763325901154f*nz*(5.f*z2-3.f);
    ynm[13] = 0.4570457994644658f*nx*(1.f-5.f*z2);
    ynm[14] = 1.445305721320277f*nz*(x2-y2);
    ynm[15] = 0.5900435899266435f*nx*(-x2+3.f*y2);
    float cp0 = bc[0], cp1 = bc[1], cp2 = bc[2];
    #pragma unroll
    for (int s = 0; s < SHD; ++s) {
      cp0 = fmaf(ynm[s], Wc[(H+s)*3+0], cp0);
      cp1 = fmaf(ynm[s], Wc[(H+s)*3+1], cp1);
      cp2 = fmaf(ynm[s], Wc[(H+s)*3+2], cp2);
    }
    rayp_all[t*8+0] = tfar_c;
    rayp_all[t*8+1] = dnorm;
    rayp_all[t*8+2] = active ? 1.f : 0.f;
    rayp_all[t*8+3] = cp0;
    rayp_all[t*8+4] = cp1;
    rayp_all[t*8+5] = cp2;
    rayp_all[t*8+6] = tnear;
    rayp_all[t*8+7] = 0.f;
  }
}

// PERSISTENT BLOCKS, spill-fixed. R13 post-mortem: keeping wa[4] live across
// the ray loop pushed reg need (~140) over the (256,4) 128-reg budget ->
// 49 MB scratch writes. THIS ROUND: wa is loaded INSIDE the loop right
// before the epilogue through an asm-laundered pointer (prevents the
// compiler re-hoisting the loop-invariant loads and re-pinning 16 VGPRs
// — the R6 lesson). Reload cost: 16 B/lane/ray from L1/L2, VMEM pipe idle.
// Need returns to R11's ~120 <= 128 -> no spill, 4 persistent blocks/CU.
// LDS: Bs 32768 + As2 5120 + base/slope/ts/mask 2048 + wtot/wred 80 = 40016.
__global__ __launch_bounds__(256, 4) void nerf_render(
    const float* __restrict__ origins, const float* __restrict__ dirs,
    const float* __restrict__ u, const float* __restrict__ W1,
    const float* __restrict__ b1, const float* __restrict__ b2,
    const float* __restrict__ bd, const unsigned short* __restrict__ w2t,
    const unsigned short* __restrict__ woutf, const float* __restrict__ rayp_all,
    float* __restrict__ out)
{
  const int tid = threadIdx.x;
  const int L = tid & 63;
  const int w = tid >> 6;
  const int g = L >> 4;
  const int c = L & 15;

  __shared__ __align__(16) short Bs[16384];     // swizzled W2^T (persistent)
  __shared__ __align__(16) short As2[4 * 640];  // per-wave epilogue slab
  __shared__ __align__(16) float baseA[H];
  __shared__ __align__(16) float slopeA[H];
  __shared__ __align__(16) float ts_s[T];
  __shared__ __align__(16) float mask_s[T];
  __shared__ float wtot[4];
  __shared__ float wred[4][4];

  // ---- stage W2 ONCE (covered by first B1) ----
  {
    const float4* src = (const float4*)w2t;
    float4* dst = (float4*)Bs;
    #pragma unroll
    for (int i = 0; i < 8; ++i) dst[tid + i * 256] = src[tid + i * 256];
  }

  short* As2w = As2 + w * 640;
  const f32x2 zero2 = {0.f, 0.f};
  const float bd0 = bd[0];

  #pragma unroll 1
  for (int r = 0; r < 8; ++r) {
    const int ray = blockIdx.x * 8 + r;
    // per-ray scalars (uniform -> s_loads)
    const float tfar_c = rayp_all[ray*8+0];
    const float dnorm  = rayp_all[ray*8+1];
    const float actf   = rayp_all[ray*8+2];
    const float cpo0   = rayp_all[ray*8+3];
    const float cpo1   = rayp_all[ray*8+4];
    const float cpo2   = rayp_all[ray*8+5];
    const float tnear  = rayp_all[ray*8+6];

    // ---- per-sample setup (tid<128) ----
    if (tid < T) {
      const int tl = tid;
      const float ox = origins[ray*3+0], oy = origins[ray*3+1], oz = origins[ray*3+2];
      const float dx = dirs[ray*3+0],  dy = dirs[ray*3+1],  dz = dirs[ray*3+2];
      const bool active = actf != 0.f;
      const float ut = u[ray*T + tl];
      const float frac = ((float)tl + ut) * (1.f/(float)T);
      const float tt = tnear + (tfar_c - tnear) * frac;
      const float px = fmaf(dx, tt, ox);
      const float py = fmaf(dy, tt, oy);
      const float pz = fmaf(dz, tt, oz);
      ts_s[tl] = tt;
      const bool m = (fabsf(px) <= 1.f) && (fabsf(py) <= 1.f) && (fabsf(pz) <= 1.f) && active;
      mask_s[tl] = m ? 1.f : 0.f;
      const float w0v = W1[tl], w1v = W1[H + tl], w2v = W1[2*H + tl];
      baseA[tl]  = fmaf(ox, w0v, fmaf(oy, w1v, fmaf(oz, w2v, b1[tl])));
      slopeA[tl] = fmaf(dx, w0v, fmaf(dy, w1v, dz * w2v));
    }

    // ---- acc init = b2 (uniform global reads, L1/L2-hot) ----
    f32x4 acc[2][8];
    #pragma unroll
    for (int mt = 0; mt < 8; ++mt) {
      const float4 bv = *(const float4*)&b2[mt*16 + g*4];
      #pragma unroll
      for (int tm = 0; tm < 2; ++tm) {
        acc[tm][mt][0] = bv.x; acc[tm][mt][1] = bv.y;
        acc[tm][mt][2] = bv.z; acc[tm][mt][3] = bv.w;
      }
    }
    __syncthreads();   // B1: setup (and on r==0, stage) visible to all waves

    // ---- fused affine-layer1 + layer2 MFMA (R11-proven) ----
    const float t0 = ts_s[32*w + c];
    const float t1 = ts_s[32*w + 16 + c];
    const f32x2 tz0 = {t0, t0}, tz1 = {t1, t1};

    #pragma unroll
    for (int ks = 0; ks < 4; ++ks) {
      const int kb = ks*32 + g*8;
      const f32x4 bq0 = *(const f32x4*)&baseA[kb];
      const f32x4 bq1 = *(const f32x4*)&baseA[kb+4];
      const f32x4 sq0 = *(const f32x4*)&slopeA[kb];
      const f32x4 sq1 = *(const f32x4*)&slopeA[kb+4];
      const f32x2 b01 = {bq0[0], bq0[1]}, b23 = {bq0[2], bq0[3]};
      const f32x2 b45 = {bq1[0], bq1[1]}, b67 = {bq1[2], bq1[3]};
      const f32x2 s01 = {sq0[0], sq0[1]}, s23 = {sq0[2], sq0[3]};
      const f32x2 s45 = {sq1[0], sq1[1]}, s67 = {sq1[2], sq1[3]};
      const f32x2 a01 = __builtin_elementwise_max(__builtin_elementwise_fma(tz0, s01, b01), zero2);
      const f32x2 a23 = __builtin_elementwise_max(__builtin_elementwise_fma(tz0, s23, b23), zero2);
      const f32x2 a45 = __builtin_elementwise_max(__builtin_elementwise_fma(tz0, s45, b45), zero2);
      const f32x2 a67 = __builtin_elementwise_max(__builtin_elementwise_fma(tz0, s67, b67), zero2);
      const f32x2 e01 = __builtin_elementwise_max(__builtin_elementwise_fma(tz1, s01, b01), zero2);
      const f32x2 e23 = __builtin_elementwise_max(__builtin_elementwise_fma(tz1, s23, b23), zero2);
      const f32x2 e45 = __builtin_elementwise_max(__builtin_elementwise_fma(tz1, s45, b45), zero2);
      const f32x2 e67 = __builtin_elementwise_max(__builtin_elementwise_fma(tz1, s67, b67), zero2);
      union U { uint4 u; short8 s; } A0, A1;
      A0.u = make_uint4(pk2(a01), pk2(a23), pk2(a45), pk2(a67));
      A1.u = make_uint4(pk2(e01), pk2(e23), pk2(e45), pk2(e67));
      const int swb = ((ks*4 + g) ^ (c & 7)) * 8;   // swizzled octet (conflict-free)
      #pragma unroll
      for (int mt = 0; mt < 8; ++mt) {
        const short8 wf = *(const short8*)&Bs[(mt*16 + c)*128 + swb];
        acc[0][mt] = __builtin_amdgcn_mfma_f32_16x16x32_bf16(wf, A0.s, acc[0][mt], 0, 0, 0);
        acc[1][mt] = __builtin_amdgcn_mfma_f32_16x16x32_bf16(wf, A1.s, acc[1][mt], 0, 0, 0);
      }
    }

    // ---- epilogue: wa loaded HERE (laundered; live range = epilogue only) ----
    const unsigned short* wfp = woutf;
    asm("" : "+v"(wfp));      // defeat loop-invariant re-hoist (R6/R13 lesson)
    short8 wa[4];
    #pragma unroll
    for (int kk = 0; kk < 4; ++kk)
      wa[kk] = *(const short8*)&wfp[(kk*64 + L)*8];   // L1/L2-hot, 16B/lane

    f32x4 osig[2];
    #pragma unroll
    for (int tm = 0; tm < 2; ++tm) {
      f32x4 oacc;
      oacc[0] = 0.f; oacc[1] = 0.f; oacc[2] = 0.f; oacc[3] = 0.f;
      #pragma unroll
      for (int kk = 0; kk < 4; ++kk) {
        #pragma unroll
        for (int i = 0; i < 2; ++i) {
          const f32x4 a = acc[tm][kk*2 + i];
          const f32x2 h01 = __builtin_elementwise_max((f32x2){a[0], a[1]}, zero2);
          const f32x2 h23 = __builtin_elementwise_max((f32x2){a[2], a[3]}, zero2);
          *(uint2*)&As2w[c*40 + i*16 + g*4] = make_uint2(pk2(h01), pk2(h23));
        }
        const short8 hbf = *(const short8*)&As2w[c*40 + g*8];
        oacc = __builtin_amdgcn_mfma_f32_16x16x32_bf16(wa[kk], hbf, oacc, 0, 0, 0);
      }
      osig[tm] = oacc;   // lanes g==0 hold {sigma_pre, c0, c1, c2}
    }

    // ---- per-wave online transmittance (valid in lanes 0..15, R2-proven) ----
    const int s0 = 32*w + c, s1 = s0 + 16;
    const float ts0 = ts_s[s0], tn0 = ts_s[s0 + 1];
    const float ts1 = ts_s[s1];
    const float tn1 = (s1 < T-1) ? ts_s[s1 + 1] : tfar_c * 10.f;
    const float d0 = mask_s[s0] * (tn0 - ts0) * dnorm;
    const float d1 = mask_s[s1] * (tn1 - ts1) * dnorm;
    const float sd0 = softplus_f(osig[0][0] + bd0) * d0;
    const float sd1 = softplus_f(osig[1][0] + bd0) * d1;
    float p0 = scan16(sd0);
    const float tot0 = readlane15f(p0);
    float p1 = scan16(sd1);
    const float tot1 = readlane15f(p1);
    if (L == 0) wtot[w] = tot0 + tot1;
    __syncthreads();   // B2: wtot ready
    float pre = 0.f;
    if (w > 0) pre += wtot[0];
    if (w > 1) pre += wtot[1];
    if (w > 2) pre += wtot[2];
    const float cs0 = pre + p0;
    const float cs1 = pre + tot0 + p1;
    const float w0 = fexp(sd0 - cs0) - fexp(-cs0);   // == 0 exactly when sd == 0
    const float w1 = fexp(sd1 - cs1) - fexp(-cs1);
    float pw  = w0 + w1;
    float pxc = w0 * sigmoid_f(osig[0][1] + cpo0) + w1 * sigmoid_f(osig[1][1] + cpo0);
    float pyc = w0 * sigmoid_f(osig[0][2] + cpo1) + w1 * sigmoid_f(osig[1][2] + cpo1);
    float pzc = w0 * sigmoid_f(osig[0][3] + cpo2) + w1 * sigmoid_f(osig[1][3] + cpo2);
    #pragma unroll
    for (int off = 1; off < 16; off <<= 1) {
      pw  += __shfl_xor(pw, off);
      pxc += __shfl_xor(pxc, off);
      pyc += __shfl_xor(pyc, off);
      pzc += __shfl_xor(pzc, off);
    }
    if (L == 0) {
      wred[w][0] = pw; wred[w][1] = pxc; wred[w][2] = pyc; wred[w][3] = pzc;
    }
    __syncthreads();   // B3: wred ready; also fences ts_s before next setup
    if (tid == 0) {
      const float aw = wred[0][0] + wred[1][0] + wred[2][0] + wred[3][0];
      const float o0 = wred[0][1] + wred[1][1] + wred[2][1] + wred[3][1];
      const float o1 = wred[0][2] + wred[1][2] + wred[2][2] + wred[3][2];
      const float o2 = wred[0][3] + wred[1][3] + wred[2][3] + wred[3][3];
      const bool act = actf != 0.f;
      float4 o;
      o.x = act ? o0 : 0.f;
      o.y = act ? o1 : 0.f;
      o.z = act ? o2 : 0.f;
      o.w = act ? aw : 0.f;
      *(float4*)&out[ray*4] = o;
    }
  }
}

extern "C" void kernel_launch(void* const* d_in, const int* in_sizes, int n_in,
                              void* d_out, int out_size, void* d_ws, size_t ws_size,
                              hipStream_t stream) {
  const float* origins = (const float*)d_in[0];
  const float* dirs    = (const float*)d_in[1];
  const float* u       = (const float*)d_in[2];
  const float* W1      = (const float*)d_in[3];
  const float* b1      = (const float*)d_in[4];
  const float* W2      = (const float*)d_in[5];
  const float* b2      = (const float*)d_in[6];
  const float* Wd      = (const float*)d_in[7];
  const float* bd      = (const float*)d_in[8];
  const float* Wc      = (const float*)d_in[9];
  const float* bc      = (const float*)d_in[10];

  unsigned short* w2t      = (unsigned short*)d_ws;
  unsigned short* woutf    = (unsigned short*)((char*)d_ws + 32768);
  float*          rayp_all = (float*)((char*)d_ws + 36864);

  preprocess<<<64, 256, 0, stream>>>(W2, Wd, Wc, bc, origins, dirs,
                                     w2t, woutf, rayp_all);
  nerf_render<<<NRAYS/8, 256, 0, stream>>>(origins, dirs, u, W1, b1, b2, bd,
                                           w2t, woutf, rayp_all, (float*)d_out);
}

// Round 15
// 130.788 us; speedup vs baseline: 1.2766x; 1.2166x over previous
//
#include <hip/hip_runtime.h>
#include <math.h>

#define NRAYS 8192
#define T 128
#define H 128
#define SHD 16

using short8 = __attribute__((ext_vector_type(8))) short;
using f32x4  = __attribute__((ext_vector_type(4))) float;
using f32x2  = __attribute__((ext_vector_type(2))) float;

__device__ __forceinline__ float fexp(float x) {
  return exp2f(x * 1.44269504088896341f);
}
__device__ __forceinline__ float softplus_f(float x) {
  return fmaxf(x, 0.f) + 0.693147180559945309f * log2f(1.f + fexp(-fabsf(x)));
}
__device__ __forceinline__ float sigmoid_f(float x) {
  return __builtin_amdgcn_rcpf(1.f + fexp(-x));
}

// RNE float->bf16 (preprocess only)
__device__ __forceinline__ unsigned f2bf(float f) {
  unsigned u = __float_as_uint(f);
  return (u + 0x7fffu + ((u >> 16) & 1u)) >> 16;
}

// RNE bf16 pack of a float pair: single VALU op (v_cvt_pk_bf16_f32, gfx950)
__device__ __forceinline__ unsigned pk2(f32x2 h) {
  unsigned r;
  asm("v_cvt_pk_bf16_f32 %0, %1, %2" : "=v"(r) : "v"(h[0]), "v"(h[1]));
  return r;
}

// DPP row_shr:N add-scan step on the VALU pipe (R10/R13-proven)
template<int N>
__device__ __forceinline__ float dpp_shr0(float v) {
  return __builtin_bit_cast(float,
    __builtin_amdgcn_update_dpp(0, __builtin_bit_cast(int, v),
                                0x110 | N, 0xf, 0xf, false));
}
// 16-lane inclusive scan, pure VALU (valid within each 16-lane row)
__device__ __forceinline__ float scan16(float v) {
  v += dpp_shr0<1>(v);
  v += dpp_shr0<2>(v);
  v += dpp_shr0<4>(v);
  v += dpp_shr0<8>(v);
  return v;
}
__device__ __forceinline__ float readlane15f(float v) {
  return __builtin_bit_cast(float,
    __builtin_amdgcn_readlane(__builtin_bit_cast(int, v), 15));
}

// ---- preprocess (R1/R11 version — cheap) ----
// w2t: bf16 W2^T, XOR-swizzled: w2t[n*128 + p], octet o=(p>>3)^(n&7), k=o*8+(p&7)
// woutf[(kk*64+L)*8+j]: epilogue A-frag; rayp_all[r][8] = AABB + SH scalars.
__global__ void preprocess(const float* __restrict__ W2, const float* __restrict__ Wd,
                           const float* __restrict__ Wc, const float* __restrict__ bc,
                           const float* __restrict__ origins, const float* __restrict__ dirs,
                           unsigned short* __restrict__ w2t,
                           unsigned short* __restrict__ woutf,
                           float* __restrict__ rayp_all) {
  const int t = blockIdx.x * 256 + threadIdx.x;
  if (t < 16384) {
    const int n = t >> 7, p = t & 127;
    const int o = (p >> 3) ^ (n & 7);
    const int k = o * 8 + (p & 7);
    w2t[t] = (unsigned short)f2bf(W2[k * 128 + n]);
  }
  if (t < 2048) {
    const int kk = t >> 9, L = (t >> 3) & 63, j = t & 7;
    const int c = L & 15, g = L >> 4;
    const int k = kk * 32 + g * 8 + j;
    float v = 0.f;
    if (c == 0) v = Wd[k];
    else if (c < 4) v = Wc[k * 3 + (c - 1)];
    woutf[t] = (unsigned short)f2bf(v);
  }
  if (t < NRAYS) {
    const float ox = origins[t*3+0], oy = origins[t*3+1], oz = origins[t*3+2];
    const float dx = dirs[t*3+0],  dy = dirs[t*3+1],  dz = dirs[t*3+2];
    const float ix = 1.f/dx, iy = 1.f/dy, iz = 1.f/dz;
    const float t1x = (-1.f-ox)*ix, t2x = (1.f-ox)*ix;
    const float t1y = (-1.f-oy)*iy, t2y = (1.f-oy)*iy;
    const float t1z = (-1.f-oz)*iz, t2z = (1.f-oz)*iz;
    float tnear = fmaxf(fmaxf(fminf(t1x,t2x), fminf(t1y,t2y)), fminf(t1z,t2z));
    tnear = fmaxf(tnear, 0.f);
    const float tfar = fminf(fminf(fmaxf(t1x,t2x), fmaxf(t1y,t2y)), fmaxf(t1z,t2z));
    const bool  active = tfar > tnear;
    const float tfar_c = fmaxf(tfar, tnear + 1e-3f);
    const float dnorm = sqrtf(dx*dx + dy*dy + dz*dz);
    const float nx = dx/dnorm, ny = dy/dnorm, nz = dz/dnorm;
    const float x2 = nx*nx, y2 = ny*ny, z2 = nz*nz;
    const float xy = nx*ny, yz = ny*nz, xz = nx*nz;
    float ynm[16];
    ynm[0]  = 0.282094791773878f;
    ynm[1]  = -0.48860251190292f*ny;
    ynm[2]  = 0.48860251190292f*nz;
    ynm[3]  = -0.48860251190292f*nx;
    ynm[4]  = 1.0925484305920792f*xy;
    ynm[5]  = -1.0925484305920792f*yz;
    ynm[6]  = 0.94617469575756f*z2 - 0.31539156525252f;
    ynm[7]  = -1.0925484305920792f*xz;
    ynm[8]  = 0.5462742152960396f*(x2-y2);
    ynm[9]  = 0.5900435899266435f*ny*(-3.f*x2+y2);
    ynm[10] = 2.8906114426405538f*xy*nz;
    ynm[11] = 0.4570457994644658f*ny*(1.f-5.f*z2);
    ynm[12] = 0.3731763325901154f*nz*(5.f*z2-3.f);
    ynm[13] = 0.4570457994644658f*nx*(1.f-5.f*z2);
    ynm[14] = 1.445305721320277f*nz*(x2-y2);
    ynm[15] = 0.5900435899266435f*nx*(-x2+3.f*y2);
    float cp0 = bc[0], cp1 = bc[1], cp2 = bc[2];
    #pragma unroll
    for (int s = 0; s < SHD; ++s) {
      cp0 = fmaf(ynm[s], Wc[(H+s)*3+0], cp0);
      cp1 = fmaf(ynm[s], Wc[(H+s)*3+1], cp1);
      cp2 = fmaf(ynm[s], Wc[(H+s)*3+2], cp2);
    }
    rayp_all[t*8+0] = tfar_c;
    rayp_all[t*8+1] = dnorm;
    rayp_all[t*8+2] = active ? 1.f : 0.f;
    rayp_all[t*8+3] = cp0;
    rayp_all[t*8+4] = cp1;
    rayp_all[t*8+5] = cp2;
    rayp_all[t*8+6] = tnear;
    rayp_all[t*8+7] = 0.f;
  }
}

// One ray per block (R11 structure, best scored 132.3) + PER-WAVE TAIL:
// R13/R14's register-resident transmittance (scan16 DPP + readlane + 4-way
// wtot stitch) replaces R11's SredP round-trip (LDS write -> barrier ->
// re-read in a different mapping -> 64-wide shfl scan with half the block
// idle). Saves one barrier + SredP traffic + the idle phase. Persistence
// (R13/R14) is abandoned: loop-carried state cannot fit the 128-reg budget
// at 4 blocks/CU (two spill strikes).
// LDS: Bs 32768 + baseA/slopeA/ts/mask 2048 + wtot 16 + wred 64 ~= 34.9 KB.
__global__ __launch_bounds__(256, 4) void nerf_render(
    const float* __restrict__ origins, const float* __restrict__ dirs,
    const float* __restrict__ u, const float* __restrict__ W1,
    const float* __restrict__ b1, const float* __restrict__ b2,
    const float* __restrict__ bd, const unsigned short* __restrict__ w2t,
    const unsigned short* __restrict__ woutf, const float* __restrict__ rayp_all,
    float* __restrict__ out)
{
  const int ray = blockIdx.x;
  const int tid = threadIdx.x;
  const int L = tid & 63;
  const int w = tid >> 6;
  const int g = L >> 4;
  const int c = L & 15;

  __shared__ __align__(16) short Bs[16384];       // swizzled W2^T; aliased post-barrier
  __shared__ __align__(16) float baseA[H];        // affine layer-1 SoA
  __shared__ __align__(16) float slopeA[H];
  __shared__ __align__(16) float ts_s[T];
  __shared__ __align__(16) float mask_s[T];
  __shared__ float wtot[4];
  __shared__ float wred[4][4];

  // per-ray scalars (wave-uniform -> scalar loads; written by preprocess)
  const float tfar_c = rayp_all[ray*8+0];
  const float dnorm  = rayp_all[ray*8+1];
  const float actf   = rayp_all[ray*8+2];
  const float cpo0   = rayp_all[ray*8+3];
  const float cpo1   = rayp_all[ray*8+4];
  const float cpo2   = rayp_all[ray*8+5];
  const float tnear  = rayp_all[ray*8+6];
  const float bd0    = bd[0];

  // ---- stage W2 (LDS), proven float4 path ----
  {
    const float4* src = (const float4*)w2t;
    float4* dst = (float4*)Bs;
    #pragma unroll
    for (int i = 0; i < 8; ++i) dst[tid + i * 256] = src[tid + i * 256];
  }

  // ---- per-sample setup (tid<128): samples + affine layer-1 coefficients ----
  if (tid < T) {
    const int tl = tid;
    const float ox = origins[ray*3+0], oy = origins[ray*3+1], oz = origins[ray*3+2];
    const float dx = dirs[ray*3+0],  dy = dirs[ray*3+1],  dz = dirs[ray*3+2];
    const bool active = actf != 0.f;
    const float ut = u[ray*T + tl];
    const float frac = ((float)tl + ut) * (1.f/(float)T);
    const float tt = tnear + (tfar_c - tnear) * frac;
    const float px = fmaf(dx, tt, ox);
    const float py = fmaf(dy, tt, oy);
    const float pz = fmaf(dz, tt, oz);
    ts_s[tl] = tt;
    const bool m = (fabsf(px) <= 1.f) && (fabsf(py) <= 1.f) && (fabsf(pz) <= 1.f) && active;
    mask_s[tl] = m ? 1.f : 0.f;
    const float w0v = W1[tl], w1v = W1[H + tl], w2v = W1[2*H + tl];
    baseA[tl]  = fmaf(ox, w0v, fmaf(oy, w1v, fmaf(oz, w2v, b1[tl])));
    slopeA[tl] = fmaf(dx, w0v, fmaf(dy, w1v, dz * w2v));
  }

  // ---- acc init = b2 (uniform global reads, L2-hot) ----
  f32x4 acc[2][8];
  #pragma unroll
  for (int mt = 0; mt < 8; ++mt) {
    const float4 bv = *(const float4*)&b2[mt*16 + g*4];
    #pragma unroll
    for (int tm = 0; tm < 2; ++tm) {
      acc[tm][mt][0] = bv.x; acc[tm][mt][1] = bv.y;
      acc[tm][mt][2] = bv.z; acc[tm][mt][3] = bv.w;
    }
  }
  __syncthreads();   // B1: stage + setup visible

  // ---- fused affine-layer1 (packed VALU) + layer2 (MFMA, W2 frags from LDS) ----
  const float t0 = ts_s[32*w + c];
  const float t1 = ts_s[32*w + 16 + c];
  const f32x2 tz0 = {t0, t0}, tz1 = {t1, t1};
  const f32x2 zero2 = {0.f, 0.f};

  #pragma unroll
  for (int ks = 0; ks < 4; ++ks) {
    const int kb = ks*32 + g*8;
    const f32x4 bq0 = *(const f32x4*)&baseA[kb];
    const f32x4 bq1 = *(const f32x4*)&baseA[kb+4];
    const f32x4 sq0 = *(const f32x4*)&slopeA[kb];
    const f32x4 sq1 = *(const f32x4*)&slopeA[kb+4];
    const f32x2 b01 = {bq0[0], bq0[1]}, b23 = {bq0[2], bq0[3]};
    const f32x2 b45 = {bq1[0], bq1[1]}, b67 = {bq1[2], bq1[3]};
    const f32x2 s01 = {sq0[0], sq0[1]}, s23 = {sq0[2], sq0[3]};
    const f32x2 s45 = {sq1[0], sq1[1]}, s67 = {sq1[2], sq1[3]};
    const f32x2 a01 = __builtin_elementwise_max(__builtin_elementwise_fma(tz0, s01, b01), zero2);
    const f32x2 a23 = __builtin_elementwise_max(__builtin_elementwise_fma(tz0, s23, b23), zero2);
    const f32x2 a45 = __builtin_elementwise_max(__builtin_elementwise_fma(tz0, s45, b45), zero2);
    const f32x2 a67 = __builtin_elementwise_max(__builtin_elementwise_fma(tz0, s67, b67), zero2);
    const f32x2 e01 = __builtin_elementwise_max(__builtin_elementwise_fma(tz1, s01, b01), zero2);
    const f32x2 e23 = __builtin_elementwise_max(__builtin_elementwise_fma(tz1, s23, b23), zero2);
    const f32x2 e45 = __builtin_elementwise_max(__builtin_elementwise_fma(tz1, s45, b45), zero2);
    const f32x2 e67 = __builtin_elementwise_max(__builtin_elementwise_fma(tz1, s67, b67), zero2);
    union U { uint4 u; short8 s; } A0, A1;
    A0.u = make_uint4(pk2(a01), pk2(a23), pk2(a45), pk2(a67));
    A1.u = make_uint4(pk2(e01), pk2(e23), pk2(e45), pk2(e67));
    const int swb = ((ks*4 + g) ^ (c & 7)) * 8;   // swizzled octet (conflict-free)
    #pragma unroll
    for (int mt = 0; mt < 8; ++mt) {
      const short8 wf = *(const short8*)&Bs[(mt*16 + c)*128 + swb];
      acc[0][mt] = __builtin_amdgcn_mfma_f32_16x16x32_bf16(wf, A0.s, acc[0][mt], 0, 0, 0);
      acc[1][mt] = __builtin_amdgcn_mfma_f32_16x16x32_bf16(wf, A1.s, acc[1][mt], 0, 0, 0);
    }
  }
  __syncthreads();   // B2: all waves done with Bs -> safe to alias As2 onto it
  short* As2 = Bs + 2048;   // bytes [4096, 24576): per-wave per-kk slabs (R11-proven)

  // ---- epilogue: relu -> bf16 slab (PER-KK DISJOINT) -> MFMA dot with Wout ----
  short* As2w = As2 + w * 2560;
  short8 wa[4];
  #pragma unroll
  for (int kk = 0; kk < 4; ++kk)
    wa[kk] = *(const short8*)&woutf[(kk*64 + L)*8];   // global, L2-hot

  f32x4 osig[2];
  #pragma unroll
  for (int tm = 0; tm < 2; ++tm) {
    // phase 1: all writes (independent, pipeline freely)
    #pragma unroll
    for (int kk = 0; kk < 4; ++kk) {
      #pragma unroll
      for (int i = 0; i < 2; ++i) {
        const f32x4 a = acc[tm][kk*2 + i];
        const f32x2 h01 = __builtin_elementwise_max((f32x2){a[0], a[1]}, zero2);
        const f32x2 h23 = __builtin_elementwise_max((f32x2){a[2], a[3]}, zero2);
        *(uint2*)&As2w[kk*640 + c*40 + i*16 + g*4] = make_uint2(pk2(h01), pk2(h23));
      }
    }
    // phase 2: reads + chained MFMA (reads all in flight; only oacc chains)
    f32x4 oacc;
    oacc[0] = 0.f; oacc[1] = 0.f; oacc[2] = 0.f; oacc[3] = 0.f;
    #pragma unroll
    for (int kk = 0; kk < 4; ++kk) {
      const short8 hbf = *(const short8*)&As2w[kk*640 + c*40 + g*8];
      oacc = __builtin_amdgcn_mfma_f32_16x16x32_bf16(wa[kk], hbf, oacc, 0, 0, 0);
    }
    osig[tm] = oacc;   // lanes g==0 hold {sigma_pre, c0, c1, c2} for sample 32w+16tm+c
  }

  // ---- per-wave transmittance, register-resident (R13/R14-proven tail) ----
  const int s0 = 32*w + c, s1 = s0 + 16;
  const float ts0 = ts_s[s0], tn0 = ts_s[s0 + 1];
  const float ts1 = ts_s[s1];
  const float tn1 = (s1 < T-1) ? ts_s[s1 + 1] : tfar_c * 10.f;
  const float d0 = mask_s[s0] * (tn0 - ts0) * dnorm;
  const float d1 = mask_s[s1] * (tn1 - ts1) * dnorm;
  const float sd0 = softplus_f(osig[0][0] + bd0) * d0;
  const float sd1 = softplus_f(osig[1][0] + bd0) * d1;
  float p0 = scan16(sd0);            // VALU (DPP), lanes 0..15 valid
  const float tot0 = readlane15f(p0);
  float p1 = scan16(sd1);
  const float tot1 = readlane15f(p1);
  if (L == 0) wtot[w] = tot0 + tot1;
  __syncthreads();   // B3: wtot ready
  float pre = 0.f;
  if (w > 0) pre += wtot[0];
  if (w > 1) pre += wtot[1];
  if (w > 2) pre += wtot[2];
  const float cs0 = pre + p0;
  const float cs1 = pre + tot0 + p1;
  const float w0 = fexp(sd0 - cs0) - fexp(-cs0);   // == 0 exactly when sd == 0
  const float w1 = fexp(sd1 - cs1) - fexp(-cs1);
  float pw  = w0 + w1;
  float pxc = w0 * sigmoid_f(osig[0][1] + cpo0) + w1 * sigmoid_f(osig[1][1] + cpo0);
  float pyc = w0 * sigmoid_f(osig[0][2] + cpo1) + w1 * sigmoid_f(osig[1][2] + cpo1);
  float pzc = w0 * sigmoid_f(osig[0][3] + cpo2) + w1 * sigmoid_f(osig[1][3] + cpo2);
  #pragma unroll
  for (int off = 1; off < 16; off <<= 1) {
    pw  += __shfl_xor(pw, off);
    pxc += __shfl_xor(pxc, off);
    pyc += __shfl_xor(pyc, off);
    pzc += __shfl_xor(pzc, off);
  }
  if (L == 0) {
    wred[w][0] = pw; wred[w][1] = pxc; wred[w][2] = pyc; wred[w][3] = pzc;
  }
  __syncthreads();   // B4: wred ready
  if (tid == 0) {
    const float aw = wred[0][0] + wred[1][0] + wred[2][0] + wred[3][0];
    const float o0 = wred[0][1] + wred[1][1] + wred[2][1] + wred[3][1];
    const float o1 = wred[0][2] + wred[1][2] + wred[2][2] + wred[3][2];
    const float o2 = wred[0][3] + wred[1][3] + wred[2][3] + wred[3][3];
    const bool act = actf != 0.f;
    float4 o;
    o.x = act ? o0 : 0.f;
    o.y = act ? o1 : 0.f;
    o.z = act ? o2 : 0.f;
    o.w = act ? aw : 0.f;
    *(float4*)&out[ray*4] = o;
  }
}

extern "C" void kernel_launch(void* const* d_in, const int* in_sizes, int n_in,
                              void* d_out, int out_size, void* d_ws, size_t ws_size,
                              hipStream_t stream) {
  const float* origins = (const float*)d_in[0];
  const float* dirs    = (const float*)d_in[1];
  const float* u       = (const float*)d_in[2];
  const float* W1      = (const float*)d_in[3];
  const float* b1      = (const float*)d_in[4];
  const float* W2      = (const float*)d_in[5];
  const float* b2      = (const float*)d_in[6];
  const float* Wd      = (const float*)d_in[7];
  const float* bd      = (const float*)d_in[8];
  const float* Wc      = (const float*)d_in[9];
  const float* bc      = (const float*)d_in[10];

  unsigned short* w2t      = (unsigned short*)d_ws;
  unsigned short* woutf    = (unsigned short*)((char*)d_ws + 32768);
  float*          rayp_all = (float*)((char*)d_ws + 36864);

  preprocess<<<64, 256, 0, stream>>>(W2, Wd, Wc, bc, origins, dirs,
                                     w2t, woutf, rayp_all);
  nerf_render<<<NRAYS, 256, 0, stream>>>(origins, dirs, u, W1, b1, b2, bd,
                                         w2t, woutf, rayp_all, (float*)d_out);
}